// Round 13
// baseline (894.585 us; speedup 1.0000x reference)
//
#include <hip/hip_runtime.h>
#include <hip/hip_cooperative_groups.h>
#include <hip/hip_bf16.h>
#include <math.h>

namespace cg = cooperative_groups;

#define B_  4
#define C_  64
#define H_  128
#define W_  128
#define HS  64
#define WS  64
#define L_  4096
#define K1  576
#define E2  1024
// f16 subnormal floor is 2^-24 (logit -16.635); values below 2^-25 (-17.33) cast
// to exactly 0. Flag threshold -17.5 is conservative: no nonzero f16 is missed.
#define ZLOG (-17.5f)

typedef _Float16 f16;
typedef f16 f16x8 __attribute__((ext_vector_type(8)));
typedef float f32x4 __attribute__((ext_vector_type(4)));

__device__ __forceinline__ void gload16(const void* g, void* l) {
    __builtin_amdgcn_global_load_lds(
        (const __attribute__((address_space(1))) unsigned int*)g,
        (__attribute__((address_space(3))) unsigned int*)l, 16, 0, 0);
}

// swizzled f16 index into a 128x128 LDS tile: 16B chunk XOR'd by row&7
__device__ __forceinline__ int swz(int r, int c) {
    return r * 128 + ((((c >> 3) ^ (r & 7)) << 3) | (c & 7));
}

// next flag-valid K position (64-elem chunk granularity, flags per 128)
__device__ __forceinline__ int nextk(int kn, int kLen, unsigned long long mask) {
    while (kn < kLen) {
        int t = kn >> 7;
        if (mask & (1ull << t)) return kn;
        unsigned long long m = mask >> t;
        if (!m) return kLen;
        kn = (t + __builtin_ctzll(m)) << 7;
    }
    return kn;
}

// ---------------- one 128x128 GEMM tile (r12-proven loop + epilogues) ----------------
// 8 waves (512 thr, 2x4 of 64x32), acc[4][2], 2-deep counted-vmcnt pipeline,
// T2 chunk XOR-swizzle (0 conflicts), coalesced LDS-staged stores.
// EPI=1: E tile pair (both triangles), max-logit pre-pass skips exp/stores for
//   all-zero tiles (f16-exact), rowsum atomics, per-tile flags; nrm = sum-sq.
// EPI=0: flag-skipped K (ballot mask), coalesced OPT tile store.
// Trailing __syncthreads guards LDS reuse by the caller's next slot.
template <int EPI>
__device__ __forceinline__ void gemm_slot(
    int by, int bx,
    const f16* __restrict__ A, const f16* __restrict__ Bt,
    int lda, int ldb, int kLen, f16* __restrict__ outbase, int ldc,
    const float* __restrict__ nrm, float* __restrict__ rowsum,
    int* __restrict__ flags,
    f16* __restrict__ AsB, f16* __restrict__ BsB, float* __restrict__ sred)
{
    const int tid = threadIdx.x;
    const int w = tid >> 6, lane = tid & 63;
    const int row0 = by * 128, col0 = bx * 128;

    unsigned long long kmask = ~0ull;
    if (EPI == 0) {
        int f = (lane < 32) ? flags[bx * 32 + lane] : 0;
        kmask = __ballot(f != 0);
    }

    // staging: thread t loads 16B for LDS row (t>>2), chunk-slot (t&3);
    // source col chunk = slot ^ ((row>>1)&3) = (t&3) ^ ((t>>3)&3)
    const int srow = tid >> 2;
    const int scol = (((tid & 3) ^ ((tid >> 3) & 3)) * 8);
    const f16* gA = A + (size_t)(row0 + srow) * lda + scol;
    const f16* gB = Bt + (size_t)(col0 + srow) * ldb + scol;
    const int ld = tid * 8;

    const int wm = w >> 2, wn = w & 3;   // 2x4 wave grid: 64x32 per wave
    const int mfm = lane & 15, quad = lane >> 4;
    const int rq = (quad ^ ((mfm >> 1) & 3)) * 8;
    f32x4 acc[4][2] = {};

    int kc = (EPI == 0) ? nextk(0, kLen, kmask) : 0;
    if (kc < kLen) {
        int cur = 0;
        gload16(gA + kc,      AsB + ld);
        gload16(gA + kc + 32, AsB + 4096 + ld);
        gload16(gB + kc,      BsB + ld);
        gload16(gB + kc + 32, BsB + 4096 + ld);
        for (;;) {
            int kn = (EPI == 0) ? nextk(kc + 64, kLen, kmask) : kc + 64;
            // (a) all waves done ds_reading buf[nxt] from iteration t-1
            __builtin_amdgcn_s_barrier();
            if (kn < kLen) {
                const int nxt = cur ^ 1;
                gload16(gA + kn,      AsB + nxt * 8192 + ld);
                gload16(gA + kn + 32, AsB + nxt * 8192 + 4096 + ld);
                gload16(gB + kn,      BsB + nxt * 8192 + ld);
                gload16(gB + kn + 32, BsB + nxt * 8192 + 4096 + ld);
                asm volatile("s_waitcnt vmcnt(4)" ::: "memory");
            } else {
                asm volatile("s_waitcnt vmcnt(0)" ::: "memory");
            }
            // (b) cur buffer complete for ALL waves
            __builtin_amdgcn_s_barrier();
            __builtin_amdgcn_sched_barrier(0);
            #pragma unroll
            for (int h = 0; h < 2; ++h) {
                const f16* Ab = AsB + cur * 8192 + h * 4096;
                const f16* Bb = BsB + cur * 8192 + h * 4096;
                f16x8 af[4], bf[2];
                #pragma unroll
                for (int mi = 0; mi < 4; ++mi)
                    af[mi] = *(const f16x8*)&Ab[(wm * 64 + mi * 16 + mfm) * 32 + rq];
                #pragma unroll
                for (int ni = 0; ni < 2; ++ni)
                    bf[ni] = *(const f16x8*)&Bb[(wn * 32 + ni * 16 + mfm) * 32 + rq];
                #pragma unroll
                for (int mi = 0; mi < 4; ++mi)
                    #pragma unroll
                    for (int ni = 0; ni < 2; ++ni)
                        acc[mi][ni] = __builtin_amdgcn_mfma_f32_16x16x32_f16(
                            af[mi], bf[ni], acc[mi][ni], 0, 0, 0);
            }
            cur ^= 1;
            kc = kn;
            if (kc >= kLen) break;
        }
    }

    const int orow = row0 + wm * 64;
    const int ocol = col0 + wn * 32;
    f16* st = AsB;   // 128x128 f16 tile (32 KB, spans both As buffers)

    if (EPI == 1) {
        f16* Eo = outbase;
        const bool offd = (by != bx);
        float rowm[16], csr[16], cs[2], cm2[2];
        #pragma unroll
        for (int j = 0; j < 16; ++j) {
            float n = fmaxf(sqrtf(nrm[orow + (j >> 2) * 16 + quad * 4 + (j & 3)]), 1e-4f);
            rowm[j] = 10.0f * n; csr[j] = 10.0f / n;
        }
        #pragma unroll
        for (int ni = 0; ni < 2; ++ni) {
            float n = fmaxf(sqrtf(nrm[ocol + ni * 16 + mfm]), 1e-4f);
            cs[ni] = 10.0f / n; cm2[ni] = 10.0f * n;
        }
        float mx1 = -1e30f, mx2 = -1e30f;
        #pragma unroll
        for (int ni = 0; ni < 2; ++ni)
            #pragma unroll
            for (int mi = 0; mi < 4; ++mi)
                #pragma unroll
                for (int r = 0; r < 4; ++r) {
                    float a = acc[mi][ni][r];
                    mx1 = fmaxf(mx1, a * cs[ni] - rowm[mi * 4 + r]);
                    mx2 = fmaxf(mx2, a * csr[mi * 4 + r] - cm2[ni]);
                }
        #pragma unroll
        for (int off = 32; off; off >>= 1) {
            mx1 = fmaxf(mx1, __shfl_xor(mx1, off));
            mx2 = fmaxf(mx2, __shfl_xor(mx2, off));
        }
        if (lane == 0) { sred[w] = mx1; sred[8 + w] = mx2; }
        __syncthreads();   // also separates last chunk's ds_reads from st reuse
        float b1 = sred[0], b2 = sred[8];
        #pragma unroll
        for (int k = 1; k < 8; ++k) {
            b1 = fmaxf(b1, sred[k]); b2 = fmaxf(b2, sred[8 + k]);
        }
        int nz1 = b1 > ZLOG;
        int nz2 = offd && (b2 > ZLOG);
        if (nz1) {
            float rs[16] = {};
            #pragma unroll
            for (int ni = 0; ni < 2; ++ni)
                #pragma unroll
                for (int mi = 0; mi < 4; ++mi)
                    #pragma unroll
                    for (int r = 0; r < 4; ++r) {
                        float e = __expf(acc[mi][ni][r] * cs[ni] - rowm[mi * 4 + r]);
                        rs[mi * 4 + r] += e;
                        st[swz(wm * 64 + mi * 16 + quad * 4 + r,
                               wn * 32 + ni * 16 + mfm)] = (f16)e;
                    }
            __syncthreads();
            #pragma unroll
            for (int it = 0; it < 4; ++it) {
                int chunk = it * 512 + tid;
                int row = chunk >> 4, c16 = chunk & 15;
                f16x8 v = *(const f16x8*)&st[row * 128 + ((c16 ^ (row & 7)) << 3)];
                *(f16x8*)&Eo[(size_t)(row0 + row) * ldc + col0 + c16 * 8] = v;
            }
            #pragma unroll
            for (int j = 0; j < 16; ++j) {
                float v = rs[j];
                v += __shfl_xor(v, 1); v += __shfl_xor(v, 2);
                v += __shfl_xor(v, 4); v += __shfl_xor(v, 8);
                if (mfm == 0)
                    atomicAdd(&rowsum[orow + (j >> 2) * 16 + quad * 4 + (j & 3)], v);
            }
        }
        if (nz2) {
            __syncthreads();   // protect st from tile1 readback
            float rs2[2] = {};
            #pragma unroll
            for (int ni = 0; ni < 2; ++ni)
                #pragma unroll
                for (int mi = 0; mi < 4; ++mi)
                    #pragma unroll
                    for (int r = 0; r < 4; ++r) {
                        float e = __expf(acc[mi][ni][r] * csr[mi * 4 + r] - cm2[ni]);
                        rs2[ni] += e;
                        st[swz(wn * 32 + ni * 16 + mfm,
                               wm * 64 + mi * 16 + quad * 4 + r)] = (f16)e;
                    }
            __syncthreads();
            #pragma unroll
            for (int it = 0; it < 4; ++it) {
                int chunk = it * 512 + tid;
                int row = chunk >> 4, c16 = chunk & 15;
                f16x8 v = *(const f16x8*)&st[row * 128 + ((c16 ^ (row & 7)) << 3)];
                *(f16x8*)&Eo[(size_t)(col0 + row) * ldc + row0 + c16 * 8] = v;
            }
            #pragma unroll
            for (int ni = 0; ni < 2; ++ni) {
                float v = rs2[ni];
                v += __shfl_xor(v, 16); v += __shfl_xor(v, 32);
                if (quad == 0)
                    atomicAdd(&rowsum[ocol + ni * 16 + mfm], v);
            }
        }
        if (tid == 0) {
            flags[by * 32 + bx] = nz1;
            if (offd) flags[bx * 32 + by] = nz2;
        }
    } else {
        __syncthreads();   // last chunk's ds_reads must finish before st reuse
        #pragma unroll
        for (int ni = 0; ni < 2; ++ni)
            #pragma unroll
            for (int mi = 0; mi < 4; ++mi)
                #pragma unroll
                for (int r = 0; r < 4; ++r)
                    st[swz(wm * 64 + mi * 16 + quad * 4 + r,
                           wn * 32 + ni * 16 + mfm)] = (f16)acc[mi][ni][r];
        __syncthreads();
        f16* base = outbase + (size_t)row0 * ldc + col0;
        #pragma unroll
        for (int it = 0; it < 4; ++it) {
            int chunk = it * 512 + tid;
            int row = chunk >> 4, c16 = chunk & 15;
            f16x8 v = *(const f16x8*)&st[row * 128 + ((c16 ^ (row & 7)) << 3)];
            *(f16x8*)&base[(size_t)row * ldc + c16 * 8] = v;
        }
    }
    __syncthreads();   // guard LDS reuse by the next slot
}

// ---------------- single cooperative mega-kernel: all phases, one dispatch ----------------
// r13: the r12 ledger closed at ~90 us of inter-dispatch gaps across 9
// dispatches (work sum ~160 us vs total 249). This fuses ALL phases into one
// cooperative launch with grid.sync() phase boundaries (~3 us each, 8 total):
// P0 zero+resize | P1 patch+normsq | P2 gemm1 (4-5 XCD-pinned slots/block,
// all 4 samples) | 2x { v | gemm0 (flag-skipped) | gather }.
// Workspace identical to r12 (174.2 MB proven); OPT overlays dead fgs+P.
// Co-residency: 66 KB LDS, launch_bounds(512,4) -> 2 blocks/CU -> 512 blocks.
__global__ __launch_bounds__(512, 4)
void mega_kernel(const float* __restrict__ bg, const float* __restrict__ fg,
                 float* __restrict__ out, char* __restrict__ w8)
{
    __shared__ __align__(16) f16 AsB[2 * 2 * 4096];
    __shared__ __align__(16) f16 BsB[2 * 2 * 4096];
    __shared__ float sred[16];

    cg::grid_group gg = cg::this_grid();
    const int NT = gridDim.x * 512;
    const int gtid = blockIdx.x * 512 + threadIdx.x;

    float* fgs        = (float*)(w8);                 //  4,194,304
    f16*   P_all      = (f16*)  (w8 + 4194304);       // 18,874,368
    float* nrmsq      = (float*)(w8 + 23068672);      //     65,536
    float* rowsum_all = (float*)(w8 + 23134208);      //     65,536
    int*   flags      = (int*)  (w8 + 23199744);      //     16,384
    const size_t EB = (size_t)L_ * L_;
    f16* Eb_all  = (f16*)(w8 + 23216128);             // 134,217,728
    f16* VT_all  = (f16*)(w8 + 23216128 + 4 * EB * 2);//  16,777,216 (2 samples)
    f16* OPT_all = (f16*)w8;                          // overlays fgs+P (dead after P2)

    // ---- P0: zero nrmsq+rowsum (contiguous 32768 f32) + bilinear resize ----
    for (int i = gtid; i < 32768; i += NT) nrmsq[i] = 0.f;
    for (int idx = gtid; idx < B_ * C_ * HS * WS; idx += NT) {
        int j = idx & 63, i = (idx >> 6) & 63, bc = idx >> 12;
        const float sc = 127.0f / 63.0f;
        float yf = i * sc, xf = j * sc;
        int y0 = (int)floorf(yf); if (y0 > 127) y0 = 127;
        int x0 = (int)floorf(xf); if (x0 > 127) x0 = 127;
        int y1 = min(y0 + 1, 127), x1 = min(x0 + 1, 127);
        float wy = yf - (float)y0, wx = xf - (float)x0;
        const float* p = fg + (size_t)bc * (H_ * W_);
        float a = p[y0 * W_ + x0], b = p[y0 * W_ + x1];
        float c = p[y1 * W_ + x0], d = p[y1 * W_ + x1];
        float t0 = a * (1.f - wy) + c * wy;
        float t1 = b * (1.f - wy) + d * wy;
        fgs[idx] = t0 * (1.f - wx) + t1 * wx;
    }
    __threadfence();
    gg.sync();

    // ---- P1: P[l,k] f16 patches + fused norm-sq (wave reduce + atomic) ----
    // 64 | 576 and loop stride is a multiple of 64, so each wave lies within
    // one (b,l) row -> full-wave shfl reduce + 1 atomic per wave.
    for (int idx = gtid; idx < B_ * L_ * K1; idx += NT) {
        int b = idx / (L_ * K1);
        int rem = idx - b * (L_ * K1);
        int k = rem % K1, l = rem / K1;
        int c = k / 9, r = k % 9;
        int dy = r / 3, dx = r % 3;
        int ly = l >> 6, lx = l & 63;
        int y = ly - 1 + dy, x = lx - 1 + dx;
        float v = 0.f;
        if ((unsigned)y < 64u && (unsigned)x < 64u)
            v = fgs[((size_t)b * C_ + c) * (HS * WS) + y * WS + x];
        P_all[idx] = (f16)v;
        float s = v * v;
        #pragma unroll
        for (int off = 32; off; off >>= 1) s += __shfl_down(s, off);
        if ((threadIdx.x & 63) == 0) atomicAdd(&nrmsq[b * L_ + l], s);
    }
    __threadfence();
    gg.sync();

    // ---- P2: E gemm for ALL 4 samples, 2176 XCD-pinned slots ----
    {
        const int xcd = blockIdx.x & 7, bi = blockIdx.x >> 3;
        const int bpx = gridDim.x >> 3;
        for (int qx = bi; qx < 272; qx += bpx) {
            int s = xcd * 272 + qx;
            int R = s / 136, q = s - R * 136;
            int ls = R >> 2, rr = R & 3, by = 0, bx = 0;
            bool ok = true;
            if (rr < 2) {
                int a = 0;
                while (q >= 16 - a) { q -= 16 - a; ++a; }
                by = a + (rr << 4); bx = a + q + (rr << 4);
            } else {
                if (q >= 128) ok = false;   // filler slot
                else { by = q & 15; bx = 16 + ((rr & 1) << 3) + (q >> 4); }
            }
            if (ok)
                gemm_slot<1>(by, bx,
                    P_all + (size_t)ls * L_ * K1, P_all + (size_t)ls * L_ * K1,
                    K1, K1, K1, Eb_all + (size_t)ls * EB, L_,
                    nrmsq + (size_t)ls * L_, rowsum_all + (size_t)ls * L_,
                    flags + ls * 1024, AsB, BsB, sred);
        }
    }
    __threadfence();
    gg.sync();

    // ---- back half: 2 rounds x { v | gemm0 | gather }, 2 samples each ----
    for (int g = 0; g < B_; g += 2) {
        // VT for samples g, g+1
        for (int idx = gtid; idx < 2 * E2 * L_; idx += NT) {
            int lsv = idx >> 22, rem = idx & 4194303;
            int l = rem & 4095, e = rem >> 12;
            int c = e >> 4, r = e & 15;
            int ky = r >> 2, kx = r & 3;
            int ly = l >> 6, lx = l & 63;
            int byy = 2 * ly - 1 + ky, bxx = 2 * lx - 1 + kx;
            float v = 0.f;
            if ((unsigned)byy < 128u && (unsigned)bxx < 128u)
                v = bg[(size_t)(g + lsv) * (C_ * H_ * W_) +
                       (size_t)c * (H_ * W_) + byy * W_ + bxx];
            VT_all[idx] = (f16)v;
        }
        __threadfence();
        gg.sync();

        // OPT[e,p] = sum_l VT[e,l] * E[p,l]; 512 slots, 1 sample per XCD-half
        {
            const int xcd = blockIdx.x & 7, bi = blockIdx.x >> 3;
            const int bpx = gridDim.x >> 3;
            for (int qx = bi; qx < 64; qx += bpx) {
                int G = xcd * 64 + qx;
                int ls = G >> 8;
                int by = (G >> 5) & 7, bx = G & 31;
                gemm_slot<0>(by, bx,
                    VT_all + (size_t)ls * E2 * L_,
                    Eb_all + (size_t)(g + ls) * EB,
                    L_, L_, L_, OPT_all + (size_t)ls * E2 * L_, L_,
                    nullptr, nullptr, flags + (g + ls) * 1024, AsB, BsB, sred);
            }
        }
        __threadfence();
        gg.sync();

        // conv_transpose overlap-add gather
        for (int idx = gtid; idx < 2 * C_ * H_ * W_; idx += NT) {
            int lsg = idx >> 20, rem = idx & 1048575;
            int X = rem & 127, Y = (rem >> 7) & 127, c = rem >> 14;
            const f16* OPT = OPT_all + (size_t)lsg * E2 * L_;
            const float* rowsum = rowsum_all + (size_t)(g + lsg) * L_;
            int kyp = (Y + 1) & 1, kxp = (X + 1) & 1;
            float sum = 0.f;
            #pragma unroll
            for (int ky = kyp; ky < 4; ky += 2) {
                int py = (Y + 1 - ky) >> 1;
                if ((unsigned)py >= 64u) continue;
                #pragma unroll
                for (int kx = kxp; kx < 4; kx += 2) {
                    int px = (X + 1 - kx) >> 1;
                    if ((unsigned)px >= 64u) continue;
                    int p = py * 64 + px;
                    int e = c * 16 + ky * 4 + kx;
                    float v = (float)OPT[(size_t)e * L_ + p];
                    sum += v * __builtin_amdgcn_rcpf(rowsum[p]);
                }
            }
            out[(size_t)(g + lsg) * (C_ * H_ * W_) + rem] = 0.25f * sum;
        }
        if (g + 2 < B_) { __threadfence(); gg.sync(); }
    }
}

extern "C" void kernel_launch(void* const* d_in, const int* in_sizes, int n_in,
                              void* d_out, int out_size, void* d_ws, size_t ws_size,
                              hipStream_t stream) {
    const float* bg = (const float*)d_in[0];
    const float* fg = (const float*)d_in[1];
    float* out = (float*)d_out;
    char* w8 = (char*)d_ws;

    // co-residency check: 512 blocks needs 2 blocks/CU; fall back to 256
    int maxb = 0;
    hipOccupancyMaxActiveBlocksPerMultiprocessor(&maxb, mega_kernel, 512, 0);
    int grid = (maxb >= 2) ? 512 : 256;

    void* args[] = { (void*)&bg, (void*)&fg, (void*)&out, (void*)&w8 };
    hipLaunchCooperativeKernel(mega_kernel, dim3(grid), dim3(512), args, 0, stream);
}

// Round 14
// 245.988 us; speedup vs baseline: 3.6367x; 3.6367x over previous
//
#include <hip/hip_runtime.h>
#include <hip/hip_bf16.h>
#include <math.h>

#define B_  4
#define C_  64
#define H_  128
#define W_  128
#define HS  64
#define WS  64
#define L_  4096
#define K1  576
#define E2  1024
// f16 subnormal floor is 2^-24 (logit -16.635); values below 2^-25 (-17.33) cast
// to exactly 0. Flag threshold -17.5 is conservative: no nonzero f16 is missed.
#define ZLOG (-17.5f)

typedef _Float16 f16;
typedef f16 f16x8 __attribute__((ext_vector_type(8)));
typedef float f32x4 __attribute__((ext_vector_type(4)));

__device__ __forceinline__ void gload16(const void* g, void* l) {
    __builtin_amdgcn_global_load_lds(
        (const __attribute__((address_space(1))) unsigned int*)g,
        (__attribute__((address_space(3))) unsigned int*)l, 16, 0, 0);
}

// swizzled f16 index into a 128x128 LDS tile: 16B chunk XOR'd by row&7
__device__ __forceinline__ int swz(int r, int c) {
    return r * 128 + ((((c >> 3) ^ (r & 7)) << 3) | (c & 7));
}

// next flag-valid K position (64-elem chunk granularity, flags per 128)
__device__ __forceinline__ int nextk(int kn, int kLen, unsigned long long mask) {
    while (kn < kLen) {
        int t = kn >> 7;
        if (mask & (1ull << t)) return kn;
        unsigned long long m = mask >> t;
        if (!m) return kLen;
        kn = (t + __builtin_ctzll(m)) << 7;
    }
    return kn;
}

// ---------------- VT builder for a PAIR of samples (vectorized f16x8) ----------------
// VT[ls][e][l] = bg[ls][c= e>>4][2*(l>>6)-1+((e>>2)&3)][2*(l&63)-1+(e&3)], 0-pad.
__device__ __forceinline__ void vbuild_pair(const float* __restrict__ bg2,
                                            f16* __restrict__ VT, int t, int nthr) {
    const int nvec = (2 * E2 * L_) / 8;   // 1,048,576 vectors of 8 f16
    for (int v = t; v < nvec; v += nthr) {
        int gidx = v << 3;
        int lsv = gidx >> 22, rem = gidx & 4194303;
        int e = rem >> 12, l0 = rem & 4095;
        int c = e >> 4, r = e & 15, ky = r >> 2, kx = r & 3;
        int ly = l0 >> 6, lx0 = l0 & 63;
        int byy = 2 * ly - 1 + ky;
        const float* row = bg2 + (size_t)lsv * (C_ * H_ * W_)
                               + (size_t)c * (H_ * W_) + byy * W_;
        f16x8 o;
        #pragma unroll
        for (int i = 0; i < 8; ++i) {
            int bxx = 2 * (lx0 + i) - 1 + kx;
            float val = 0.f;
            if ((unsigned)byy < 128u && (unsigned)bxx < 128u) val = row[bxx];
            o[i] = (f16)val;
        }
        *(f16x8*)&VT[gidx] = o;
    }
}

// ---------------- conv_transpose overlap-add gather for a PAIR of samples ----------------
__device__ __forceinline__ void gather_pair(const f16* __restrict__ OPT_g,
                                            const float* __restrict__ rowsum_g,
                                            float* __restrict__ out_g,
                                            int t, int nthr) {
    for (int idx = t; idx < 2 * C_ * H_ * W_; idx += nthr) {
        int lsg = idx >> 20, rem = idx & 1048575;
        int X = rem & 127, Y = (rem >> 7) & 127, c = rem >> 14;
        const f16* OPT = OPT_g + (size_t)lsg * ((size_t)E2 * L_);
        const float* rowsum = rowsum_g + (size_t)lsg * L_;
        int kyp = (Y + 1) & 1, kxp = (X + 1) & 1;
        float sum = 0.f;
        #pragma unroll
        for (int ky = kyp; ky < 4; ky += 2) {
            int py = (Y + 1 - ky) >> 1;
            if ((unsigned)py >= 64u) continue;
            #pragma unroll
            for (int kx = kxp; kx < 4; kx += 2) {
                int px = (X + 1 - kx) >> 1;
                if ((unsigned)px >= 64u) continue;
                int p = py * 64 + px;
                int e = c * 16 + ky * 4 + kx;
                float v = (float)OPT[(size_t)e * L_ + p];
                sum += v * __builtin_amdgcn_rcpf(rowsum[p]);
            }
        }
        out_g[(size_t)lsg * (C_ * H_ * W_) + rem] = 0.25f * sum;
    }
}

// ---------------- bilinear resize 128->64 + zero nrmsq/rowsum (fused) ----------------
__global__ __launch_bounds__(256) void resize_kernel(const float* __restrict__ fg,
                                                     float* __restrict__ fgs,
                                                     float* __restrict__ nrmsq) {
    int idx = blockIdx.x * 256 + threadIdx.x;
    if (idx < 32768) nrmsq[idx] = 0.f;   // nrmsq + rowsum, contiguous
    if (idx >= B_ * C_ * HS * WS) return;
    int j = idx & 63, i = (idx >> 6) & 63, bc = idx >> 12;
    const float sc = 127.0f / 63.0f;
    float yf = i * sc, xf = j * sc;
    int y0 = (int)floorf(yf); if (y0 > 127) y0 = 127;
    int x0 = (int)floorf(xf); if (x0 > 127) x0 = 127;
    int y1 = min(y0 + 1, 127), x1 = min(x0 + 1, 127);
    float wy = yf - (float)y0, wx = xf - (float)x0;
    const float* p = fg + (size_t)bc * (H_ * W_);
    float a = p[y0 * W_ + x0], b = p[y0 * W_ + x1];
    float c = p[y1 * W_ + x0], d = p[y1 * W_ + x1];
    float t0 = a * (1.f - wy) + c * wy;
    float t1 = b * (1.f - wy) + d * wy;
    fgs[idx] = t0 * (1.f - wx) + t1 * wx;
}

// ---------------- P[l,k] f16 patches + fused norm-sq (wave reduce + atomic) ----------------
__global__ __launch_bounds__(256) void patch_kernel(const float* __restrict__ fgs,
                                                    f16* __restrict__ P_all,
                                                    float* __restrict__ nrmsq) {
    int idx = blockIdx.x * 256 + threadIdx.x;
    int b = blockIdx.y;
    int k = idx % K1, l = idx / K1;
    int c = k / 9, r = k % 9;
    int dy = r / 3, dx = r % 3;
    int ly = l >> 6, lx = l & 63;
    int y = ly - 1 + dy, x = lx - 1 + dx;
    float v = 0.f;
    if ((unsigned)y < 64u && (unsigned)x < 64u)
        v = fgs[((size_t)b * C_ + c) * (HS * WS) + y * WS + x];
    P_all[(size_t)b * L_ * K1 + idx] = (f16)v;
    float s = v * v;
    #pragma unroll
    for (int off = 32; off; off >>= 1) s += __shfl_down(s, off);
    if ((threadIdx.x & 63) == 0) atomicAdd(&nrmsq[b * L_ + l], s);
}

// ---------------- gather(s_g, s_g+1) + v-build(next pair) merged ----------------
// blocks [0, nvb): vbuild into VT (the old pair's VT is dead); rest: gather.
__global__ __launch_bounds__(512) void gv_kernel(const float* __restrict__ bg2,
                                                 f16* __restrict__ VT,
                                                 const f16* __restrict__ OPT_g,
                                                 const float* __restrict__ rowsum_g,
                                                 float* __restrict__ out_g,
                                                 int nvb) {
    if (blockIdx.x < nvb) {
        vbuild_pair(bg2, VT, blockIdx.x * 512 + threadIdx.x, nvb * 512);
    } else {
        gather_pair(OPT_g, rowsum_g, out_g,
                    (blockIdx.x - nvb) * 512 + threadIdx.x,
                    (gridDim.x - nvb) * 512);
    }
}

// ---------------- MFMA gemm_bt: D[M,N] = A[M,K] * Bt[N,K]^T ----------------
// r14 = r12 (proven pass) with dispatch consolidation. Inner loop unchanged:
// 8 waves 512 thr (2x4 of 64x32), acc[4][2], 2-deep counted-vmcnt pipeline,
// T2 chunk XOR-swizzle (0 conflicts), r4 XCD-pinned L2-locality schedule.
// NEW: blocks >= ngemm run the independent VT-build for the first sample pair
// (elementwise, no barriers) concurrently with gemm<1> -- free under its
// latency-bound 66 us. XCD slot arithmetic uses ngemm>>3 (not gridDim).
// EPI=1: nrm = sum-of-squares (fused patch-norm), both E triangles, max-logit
//   pre-pass, coalesced LDS-staged stores, rowsum atomics, per-tile flags.
// EPI=0 (PV): ballot flag mask, K-loop jumps to nonzero E-tiles only,
//   coalesced LDS-staged OPT store.
template <int EPI>
__global__ __launch_bounds__(512, 4)
void mfma_gemm(const f16* __restrict__ A, size_t sA,
               const f16* __restrict__ Bt, size_t sB,
               int lda, int ldb, int kLen, void* __restrict__ outp, size_t sOut,
               int ldc, const float* __restrict__ nrm, float* __restrict__ rowsum,
               int* __restrict__ flags,
               const float* __restrict__ vbg, f16* __restrict__ vdst, int ngemm) {
    // [buf][half][128 rows x 32 cols]; As doubles as the 128x128 f16 store tile
    __shared__ __align__(16) f16 As[2][2][128 * 32];
    __shared__ __align__(16) f16 Bs[2][2][128 * 32];
    __shared__ float sred[16];

    const int lin = blockIdx.x;
    if (lin >= ngemm) {   // fused VT-build blocks (no barriers on this path)
        vbuild_pair(vbg, vdst, (lin - ngemm) * 512 + threadIdx.x,
                    (gridDim.x - ngemm) * 512);
        return;
    }

    const int S = ngemm >> 3;
    int bx, by, ls;
    if (EPI == 1) {
        int s = (lin & 7) * S + (lin >> 3);
        int R = s / 136, q = s - R * 136;
        ls = R >> 2;
        int rr = R & 3;
        if (rr < 2) {
            int a = 0;
            while (q >= 16 - a) { q -= 16 - a; ++a; }
            by = a + (rr << 4); bx = a + q + (rr << 4);
        } else {
            if (q >= 128) return;   // idle filler slot (before any barrier)
            by = q & 15; bx = 16 + ((rr & 1) << 3) + (q >> 4);
        }
    } else {
        int G = (lin & 7) * S + (lin >> 3);
        ls = G >> 8;                      // 256 slots/sample; XCDs 0-3 -> s0, 4-7 -> s1
        by = (G >> 5) & 7; bx = G & 31;   // by: e-tile, bx: p-tile
    }

    A  += (size_t)ls * sA;
    Bt += (size_t)ls * sB;
    f16* outbase = (f16*)outp + (size_t)ls * sOut;   // strides in f16 ELEMENTS
    if (EPI == 1) { nrm += (size_t)ls * L_; rowsum += (size_t)ls * L_; }
    flags += ls * 1024;

    const int tid = threadIdx.x;
    const int w = tid >> 6, lane = tid & 63;
    const int row0 = by * 128, col0 = bx * 128;

    unsigned long long kmask = ~0ull;
    if (EPI == 0) {
        int f = (lane < 32) ? flags[bx * 32 + lane] : 0;
        kmask = __ballot(f != 0);
    }

    // staging: thread t loads 16B for LDS row (t>>2), chunk-slot (t&3);
    // source col chunk = slot ^ ((row>>1)&3) = (t&3) ^ ((t>>3)&3)
    const int srow = tid >> 2;
    const int scol = (((tid & 3) ^ ((tid >> 3) & 3)) * 8);
    const f16* gA = A + (size_t)(row0 + srow) * lda + scol;
    const f16* gB = Bt + (size_t)(col0 + srow) * ldb + scol;
    const int ld = tid * 8;   // f16 offset of this thread's 16B in a half-buf

    const int wm = w >> 2, wn = w & 3;   // 2x4 wave grid: 64x32 per wave
    const int mfm = lane & 15, quad = lane >> 4;
    const int rq = (quad ^ ((mfm >> 1) & 3)) * 8;
    f32x4 acc[4][2] = {};

    int kc = (EPI == 0) ? nextk(0, kLen, kmask) : 0;
    if (kc < kLen) {
        int cur = 0;
        gload16(gA + kc,      &As[0][0][ld]);
        gload16(gA + kc + 32, &As[0][1][ld]);
        gload16(gB + kc,      &Bs[0][0][ld]);
        gload16(gB + kc + 32, &Bs[0][1][ld]);
        for (;;) {
            int kn = (EPI == 0) ? nextk(kc + 64, kLen, kmask) : kc + 64;
            // (a) all waves done ds_reading buf[nxt] from iteration t-1
            __builtin_amdgcn_s_barrier();
            if (kn < kLen) {
                const int nxt = cur ^ 1;
                gload16(gA + kn,      &As[nxt][0][ld]);
                gload16(gA + kn + 32, &As[nxt][1][ld]);
                gload16(gB + kn,      &Bs[nxt][0][ld]);
                gload16(gB + kn + 32, &Bs[nxt][1][ld]);
                // wait only the PREVIOUS chunk's 4 loads (counted vmcnt)
                asm volatile("s_waitcnt vmcnt(4)" ::: "memory");
            } else {
                asm volatile("s_waitcnt vmcnt(0)" ::: "memory");
            }
            // (b) cur buffer complete for ALL waves
            __builtin_amdgcn_s_barrier();
            __builtin_amdgcn_sched_barrier(0);
            #pragma unroll
            for (int h = 0; h < 2; ++h) {
                f16x8 af[4], bf[2];
                #pragma unroll
                for (int mi = 0; mi < 4; ++mi)
                    af[mi] = *(const f16x8*)&As[cur][h][(wm * 64 + mi * 16 + mfm) * 32 + rq];
                #pragma unroll
                for (int ni = 0; ni < 2; ++ni)
                    bf[ni] = *(const f16x8*)&Bs[cur][h][(wn * 32 + ni * 16 + mfm) * 32 + rq];
                #pragma unroll
                for (int mi = 0; mi < 4; ++mi)
                    #pragma unroll
                    for (int ni = 0; ni < 2; ++ni)
                        acc[mi][ni] = __builtin_amdgcn_mfma_f32_16x16x32_f16(
                            af[mi], bf[ni], acc[mi][ni], 0, 0, 0);
            }
            cur ^= 1;
            kc = kn;
            if (kc >= kLen) break;
        }
    }

    const int orow = row0 + wm * 64;   // global row base of this wave's tile
    const int ocol = col0 + wn * 32;   // global col base
    f16* st = &As[0][0][0];            // 128x128 f16 tile (32 KB)

    if (EPI == 1) {
        f16* Eo = outbase;
        const bool offd = (by != bx);
        float rowm[16], csr[16], cs[2], cm2[2];
        #pragma unroll
        for (int j = 0; j < 16; ++j) {
            float n = fmaxf(sqrtf(nrm[orow + (j >> 2) * 16 + quad * 4 + (j & 3)]), 1e-4f);
            rowm[j] = 10.0f * n; csr[j] = 10.0f / n;
        }
        #pragma unroll
        for (int ni = 0; ni < 2; ++ni) {
            float n = fmaxf(sqrtf(nrm[ocol + ni * 16 + mfm]), 1e-4f);
            cs[ni] = 10.0f / n; cm2[ni] = 10.0f * n;
        }
        // max-logit pass (no exp): tile1 = E[p,l], tile2 = E[l,p] (off-diag)
        float mx1 = -1e30f, mx2 = -1e30f;
        #pragma unroll
        for (int ni = 0; ni < 2; ++ni)
            #pragma unroll
            for (int mi = 0; mi < 4; ++mi)
                #pragma unroll
                for (int r = 0; r < 4; ++r) {
                    float a = acc[mi][ni][r];
                    mx1 = fmaxf(mx1, a * cs[ni] - rowm[mi * 4 + r]);
                    mx2 = fmaxf(mx2, a * csr[mi * 4 + r] - cm2[ni]);
                }
        #pragma unroll
        for (int off = 32; off; off >>= 1) {
            mx1 = fmaxf(mx1, __shfl_xor(mx1, off));
            mx2 = fmaxf(mx2, __shfl_xor(mx2, off));
        }
        if (lane == 0) { sred[w] = mx1; sred[8 + w] = mx2; }
        __syncthreads();   // also separates last chunk's ds_reads from st reuse
        float b1 = sred[0], b2 = sred[8];
        #pragma unroll
        for (int k = 1; k < 8; ++k) {
            b1 = fmaxf(b1, sred[k]); b2 = fmaxf(b2, sred[8 + k]);
        }
        int nz1 = b1 > ZLOG;
        int nz2 = offd && (b2 > ZLOG);
        if (nz1) {
            float rs[16] = {};
            #pragma unroll
            for (int ni = 0; ni < 2; ++ni)
                #pragma unroll
                for (int mi = 0; mi < 4; ++mi)
                    #pragma unroll
                    for (int r = 0; r < 4; ++r) {
                        float e = __expf(acc[mi][ni][r] * cs[ni] - rowm[mi * 4 + r]);
                        rs[mi * 4 + r] += e;
                        st[swz(wm * 64 + mi * 16 + quad * 4 + r,
                               wn * 32 + ni * 16 + mfm)] = (f16)e;
                    }
            __syncthreads();
            #pragma unroll
            for (int it = 0; it < 4; ++it) {
                int chunk = it * 512 + tid;
                int row = chunk >> 4, c16 = chunk & 15;
                f16x8 v = *(const f16x8*)&st[row * 128 + ((c16 ^ (row & 7)) << 3)];
                *(f16x8*)&Eo[(size_t)(row0 + row) * ldc + col0 + c16 * 8] = v;
            }
            #pragma unroll
            for (int j = 0; j < 16; ++j) {
                float v = rs[j];
                v += __shfl_xor(v, 1); v += __shfl_xor(v, 2);
                v += __shfl_xor(v, 4); v += __shfl_xor(v, 8);
                if (mfm == 0)
                    atomicAdd(&rowsum[orow + (j >> 2) * 16 + quad * 4 + (j & 3)], v);
            }
        }
        if (nz2) {
            __syncthreads();   // protect st from tile1 readback
            float rs2[2] = {};
            #pragma unroll
            for (int ni = 0; ni < 2; ++ni)
                #pragma unroll
                for (int mi = 0; mi < 4; ++mi)
                    #pragma unroll
                    for (int r = 0; r < 4; ++r) {
                        float e = __expf(acc[mi][ni][r] * csr[mi * 4 + r] - cm2[ni]);
                        rs2[ni] += e;
                        st[swz(wn * 32 + ni * 16 + mfm,
                               wm * 64 + mi * 16 + quad * 4 + r)] = (f16)e;
                    }
            __syncthreads();
            #pragma unroll
            for (int it = 0; it < 4; ++it) {
                int chunk = it * 512 + tid;
                int row = chunk >> 4, c16 = chunk & 15;
                f16x8 v = *(const f16x8*)&st[row * 128 + ((c16 ^ (row & 7)) << 3)];
                *(f16x8*)&Eo[(size_t)(col0 + row) * ldc + row0 + c16 * 8] = v;
            }
            #pragma unroll
            for (int ni = 0; ni < 2; ++ni) {
                float v = rs2[ni];
                v += __shfl_xor(v, 16); v += __shfl_xor(v, 32);
                if (quad == 0)
                    atomicAdd(&rowsum[ocol + ni * 16 + mfm], v);
            }
        }
        if (tid == 0) {
            flags[by * 32 + bx] = nz1;
            if (offd) flags[bx * 32 + by] = nz2;
        }
    } else {
        __syncthreads();   // last chunk's ds_reads must finish before st reuse
        // coalesced store of the (often zero) 128x128 output tile
        #pragma unroll
        for (int ni = 0; ni < 2; ++ni)
            #pragma unroll
            for (int mi = 0; mi < 4; ++mi)
                #pragma unroll
                for (int r = 0; r < 4; ++r)
                    st[swz(wm * 64 + mi * 16 + quad * 4 + r,
                           wn * 32 + ni * 16 + mfm)] = (f16)acc[mi][ni][r];
        __syncthreads();
        f16* base = outbase + (size_t)row0 * ldc + col0;
        #pragma unroll
        for (int it = 0; it < 4; ++it) {
            int chunk = it * 512 + tid;
            int row = chunk >> 4, c16 = chunk & 15;
            f16x8 v = *(const f16x8*)&st[row * 128 + ((c16 ^ (row & 7)) << 3)];
            *(f16x8*)&base[(size_t)row * ldc + c16 * 8] = v;
        }
    }
}

extern "C" void kernel_launch(void* const* d_in, const int* in_sizes, int n_in,
                              void* d_out, int out_size, void* d_ws, size_t ws_size,
                              hipStream_t stream) {
    const float* bg = (const float*)d_in[0];
    const float* fg = (const float*)d_in[1];
    float* out = (float*)d_out;
    char* w8 = (char*)d_ws;

    // fixed workspace region (bytes)
    float* fgs        = (float*)(w8);                 //  4,194,304
    f16*   P_all      = (f16*)  (w8 + 4194304);       // 18,874,368
    float* nrmsq      = (float*)(w8 + 23068672);      //     65,536 (sum of squares)
    float* rowsum_all = (float*)(w8 + 23134208);      //     65,536 (B_ x L_)
    int*   flags      = (int*)  (w8 + 23199744);      //     16,384
    const size_t base = 23216128;

    // Eb x4 (134,217,728 B) + VT x2 (16,777,216 B) -> total 174,211,072 B,
    // exactly the r2-proven workspace bound. OPT x2 (16,777,216 B) OVERLAYS
    // the fgs+P region (23,068,672 B), which is dead after gemm<1>.
    const size_t EB_ELEMS = (size_t)L_ * L_;
    f16* Eb_all  = (f16*)(w8 + base);
    f16* VT_all  = (f16*)(w8 + base + 4 * EB_ELEMS * 2);
    f16* OPT_all = (f16*)w8;   // overlays fgs + P_all (dead after gemm<1>)

    const size_t CHW = (size_t)C_ * H_ * W_;

    // D1: resize + zero nrmsq/rowsum (fused)
    resize_kernel<<<(B_ * C_ * HS * WS) / 256, 256, 0, stream>>>(fg, fgs, nrmsq);
    // D2: patches + fused norm-sq
    patch_kernel<<<dim3((L_ * K1) / 256, B_), 256, 0, stream>>>(fgs, P_all, nrmsq);

    // D3: E for ALL 4 samples (2176 XCD-pinned slots) + fused VT build (s0,s1)
    mfma_gemm<1><<<2176 + 512, 512, 0, stream>>>(
        P_all, (size_t)L_ * K1, P_all, (size_t)L_ * K1,
        K1, K1, K1, Eb_all, EB_ELEMS, L_,
        nrmsq, rowsum_all, flags,
        bg, VT_all, 2176);

    // D4: OPT(s0,s1) = VT . E (flag-skipped K)
    mfma_gemm<0><<<512, 512, 0, stream>>>(
        VT_all, (size_t)E2 * L_, Eb_all, EB_ELEMS,
        L_, L_, L_, OPT_all, (size_t)E2 * L_, L_,
        nullptr, nullptr, flags,
        nullptr, nullptr, 512);

    // D5: gather(s0,s1) + VT build (s2,s3) merged (VT(s0,s1) dead after D4)
    gv_kernel<<<512 + 1024, 512, 0, stream>>>(
        bg + 2 * CHW, VT_all, OPT_all, rowsum_all, out, 512);

    // D6: OPT(s2,s3) = VT . E
    mfma_gemm<0><<<512, 512, 0, stream>>>(
        VT_all, (size_t)E2 * L_, Eb_all + 2 * EB_ELEMS, EB_ELEMS,
        L_, L_, L_, OPT_all, (size_t)E2 * L_, L_,
        nullptr, nullptr, flags + 2 * 1024,
        nullptr, nullptr, 512);

    // D7: gather(s2,s3)
    gv_kernel<<<1024, 512, 0, stream>>>(
        nullptr, nullptr, OPT_all, rowsum_all + 2 * L_, out + 2 * CHW, 0);
}